// Round 14
// baseline (311.651 us; speedup 1.0000x reference)
//
#include <hip/hip_runtime.h>
#include <hip/hip_bf16.h>

#define NTOT 1048576
#define NSEG 4096
#define HDIM 128
#define ODIM 256
#define BN   64
#define GRID1 1024
#define TPB  (NTOT / (BN * GRID1))   // 16 tiles per block

typedef __attribute__((ext_vector_type(8))) short bf16x8;
typedef __attribute__((ext_vector_type(4))) float f32x4;
typedef __attribute__((ext_vector_type(4))) unsigned int u32x4;

typedef const __attribute__((address_space(1))) unsigned int* gp_t;
typedef __attribute__((address_space(3))) unsigned int* lp_t;

// HW packed f32->bf16 RNE (no builtin on gfx950)
__device__ __forceinline__ unsigned int cvt_pk(float lo, float hi) {
    unsigned int r;
    asm("v_cvt_pk_bf16_f32 %0, %1, %2" : "=v"(r) : "v"(lo), "v"(hi));
    return r;
}

// zero sumx (1M floats) + convert W1 (32768 f32 -> 16384 packed u32), one dispatch
__global__ void zero_convert(const float* __restrict__ W1, unsigned int* __restrict__ W1b,
                             float* __restrict__ sumx) {
    int gid = blockIdx.x * 256 + threadIdx.x;
    sumx[gid] = 0.0f;
    if (gid < (ODIM * HDIM / 2)) {
        float2 v = *(const float2*)(W1 + 2 * gid);
        W1b[gid] = cvt_pk(v.x, v.y);
    }
}

// ======== DIAGNOSTIC: maximal pure reader of x (512 MB) ========
// 2048 blocks x 256 thr = 32 waves/CU; 8 independent f32x4 loads in flight
// per thread; per-thread sum written to scratch (keeps loads live).
// T_read = total_dur - 210us tells us the pure-read BW ceiling for x.
__global__ __launch_bounds__(256) void diag_read(const float* __restrict__ x,
                                                 float* __restrict__ out) {
    const int t = blockIdx.x * 256 + threadIdx.x;
    const int stride = 2048 * 256;
    const f32x4* xv = (const f32x4*)x;
    f32x4 a0 = {0,0,0,0}, a1 = {0,0,0,0}, a2 = {0,0,0,0}, a3 = {0,0,0,0};
    #pragma unroll
    for (int o = 0; o < 8; ++o) {
        f32x4 v0 = xv[t + (o*8+0)*stride];
        f32x4 v1 = xv[t + (o*8+1)*stride];
        f32x4 v2 = xv[t + (o*8+2)*stride];
        f32x4 v3 = xv[t + (o*8+3)*stride];
        f32x4 v4 = xv[t + (o*8+4)*stride];
        f32x4 v5 = xv[t + (o*8+5)*stride];
        f32x4 v6 = xv[t + (o*8+6)*stride];
        f32x4 v7 = xv[t + (o*8+7)*stride];
        a0 = a0 + v0 + v4;
        a1 = a1 + v1 + v5;
        a2 = a2 + v2 + v6;
        a3 = a3 + v3 + v7;
    }
    f32x4 a = a0 + a1 + a2 + a3;
    out[t] = a.x + a.y + a.z + a.w;
}

// ======== production stage1: R11 verbatim (210 us best) ========
__global__ __launch_bounds__(256, 2)
void stage1(const float* __restrict__ x, const int* __restrict__ batch,
            const unsigned short* __restrict__ W1b, const float* __restrict__ b1,
            float* __restrict__ sumx) {
    __shared__ __align__(16) float xbuf[2][BN * HDIM];   // 2 x 32 KB swizzled f32 tiles
    __shared__ int segAll[TPB * BN];                     // 4 KB

    const int t    = threadIdx.x;
    const int lane = t & 63;
    const int wv   = t >> 6;
    const int l15  = lane & 15;
    const int lhi  = (lane >> 4) & 3;

    const bool is64 = (batch[NTOT - 1] == 0);
    const long r0 = (long)blockIdx.x * (TPB * BN);
    const char* xb = (const char*)(x + r0 * HDIM);

    int soff[8];
    #pragma unroll
    for (int j = 0; j < 8; ++j) {
        int c = j * 256 + wv * 64 + lane;
        int row = c >> 5, g = c & 31;
        soff[j] = row * 512 + ((g << 4) ^ ((row & 7) << 4));
    }

    #pragma unroll
    for (int j = 0; j < 8; ++j)
        __builtin_amdgcn_global_load_lds((gp_t)(xb + soff[j]),
                                         (lp_t)((char*)&xbuf[0][0] + (j * 256 + wv * 64) * 16), 16, 0, 0);
    __builtin_amdgcn_sched_barrier(0);

    for (int i = t; i < TPB * BN; i += 256) {
        long idx = r0 + i;
        segAll[i] = batch[is64 ? 2 * idx : idx];
    }
    bf16x8 bfr[4][4];
    #pragma unroll
    for (int nf = 0; nf < 4; ++nf)
        #pragma unroll
        for (int ks = 0; ks < 4; ++ks)
            bfr[nf][ks] = *(const bf16x8*)(W1b + (wv * 64 + nf * 16 + l15) * HDIM + ks * 32 + lhi * 8);
    float bias[4];
    #pragma unroll
    for (int nf = 0; nf < 4; ++nf) bias[nf] = b1[wv * 64 + nf * 16 + l15];

    asm volatile("s_waitcnt vmcnt(0) lgkmcnt(0)" ::: "memory");
    __builtin_amdgcn_sched_barrier(0);
    __builtin_amdgcn_s_barrier();

    for (int g = 0; g < TPB; ++g) {
        const int nb = g & 1;

        if (g + 1 < TPB) {
            const char* src = xb + (size_t)(g + 1) * (BN * HDIM * 4);
            char* dst = (char*)&xbuf[nb ^ 1][0];
            #pragma unroll
            for (int j = 0; j < 8; ++j)
                __builtin_amdgcn_global_load_lds((gp_t)(src + soff[j]),
                                                 (lp_t)(dst + (j * 256 + wv * 64) * 16), 16, 0, 0);
            __builtin_amdgcn_sched_barrier(0);
            asm volatile("s_waitcnt vmcnt(8)" ::: "memory");
        } else {
            asm volatile("s_waitcnt vmcnt(0)" ::: "memory");
        }
        __builtin_amdgcn_sched_barrier(0);
        __builtin_amdgcn_s_barrier();
        __builtin_amdgcn_sched_barrier(0);

        f32x4 acc[4][4];
        #pragma unroll
        for (int nf = 0; nf < 4; ++nf) {
            const float bb = bias[nf];
            #pragma unroll
            for (int mf = 0; mf < 4; ++mf)
                acc[mf][nf] = (f32x4){bb, bb, bb, bb};
        }
        const char* tile = (const char*)&xbuf[nb][0];
        #pragma unroll
        for (int ks = 0; ks < 4; ++ks) {
            #pragma unroll
            for (int mf = 0; mf < 4; ++mf) {
                const int m  = mf * 16 + l15;
                const int rb = m * 512;
                const int kb = ks * 128 + lhi * 32;
                const int sw = (m & 7) << 4;
                f32x4 u = *(const f32x4*)(tile + rb + (kb ^ sw));
                f32x4 v = *(const f32x4*)(tile + rb + ((kb + 16) ^ sw));
                u32x4 w;
                w.x = cvt_pk(u.x, u.y); w.y = cvt_pk(u.z, u.w);
                w.z = cvt_pk(v.x, v.y); w.w = cvt_pk(v.z, v.w);
                bf16x8 af = __builtin_bit_cast(bf16x8, w);
                #pragma unroll
                for (int nf = 0; nf < 4; ++nf)
                    acc[mf][nf] = __builtin_amdgcn_mfma_f32_16x16x32_bf16(af, bfr[nf][ks], acc[mf][nf], 0, 0, 0);
            }
        }

        #pragma unroll
        for (int mf = 0; mf < 4; ++mf)
            #pragma unroll
            for (int nf = 0; nf < 4; ++nf)
                #pragma unroll
                for (int r = 0; r < 4; ++r) {
                    float e = exp2f(acc[mf][nf][r] * 2.885390081777927f);
                    acc[mf][nf][r] = 1.0f - 2.0f * __builtin_amdgcn_rcpf(1.0f + e);
                }

        const int* segc = &segAll[g * BN];
        unsigned long long bmask;
        {
            int s_here = segc[lane];
            int s_prev = (lane > 0) ? segc[lane - 1] : s_here;
            bmask = __ballot(s_here != s_prev);
        }
        int start = 0;
        unsigned long long rem = bmask;
        for (;;) {
            const int end = rem ? (int)__builtin_ctzll(rem) : BN;
            const int sid = segc[start];
            float p0 = 0.f, p1 = 0.f, p2 = 0.f, p3 = 0.f;
            #pragma unroll
            for (int mf = 0; mf < 4; ++mf)
                #pragma unroll
                for (int r = 0; r < 4; ++r) {
                    int row = mf * 16 + lhi * 4 + r;
                    float w = ((unsigned)(row - start) < (unsigned)(end - start)) ? 1.0f : 0.0f;
                    p0 = fmaf(w, acc[mf][0][r], p0);
                    p1 = fmaf(w, acc[mf][1][r], p1);
                    p2 = fmaf(w, acc[mf][2][r], p2);
                    p3 = fmaf(w, acc[mf][3][r], p3);
                }
            p0 += __shfl_xor(p0, 16); p0 += __shfl_xor(p0, 32);
            p1 += __shfl_xor(p1, 16); p1 += __shfl_xor(p1, 32);
            p2 += __shfl_xor(p2, 16); p2 += __shfl_xor(p2, 32);
            p3 += __shfl_xor(p3, 16); p3 += __shfl_xor(p3, 32);
            if (lhi == 0) {
                float* base = sumx + (long)sid * ODIM + wv * 64 + l15;
                atomicAdd(base +  0, p0);
                atomicAdd(base + 16, p1);
                atomicAdd(base + 32, p2);
                atomicAdd(base + 48, p3);
            }
            if (rem == 0) break;
            start = end;
            rem &= rem - 1;
        }

        asm volatile("s_waitcnt lgkmcnt(0)" ::: "memory");
        __builtin_amdgcn_sched_barrier(0);
        __builtin_amdgcn_s_barrier();
        __builtin_amdgcn_sched_barrier(0);
    }
}

// y[g][h] = b2[h] + sum_o sumx[g][o] * W2[h][o]   (fp32, 268 MFLOP)
__global__ __launch_bounds__(256)
void stage2(const float* __restrict__ sumx, const float* __restrict__ W2,
            const float* __restrict__ b2, float* __restrict__ y) {
    __shared__ float sx[16 * 256];
    const int t = threadIdx.x;
    const long g0 = (long)blockIdx.x * 16;
    #pragma unroll
    for (int i = 0; i < 16; ++i)
        sx[i * 256 + t] = sumx[(g0 + i) * 256 + t];
    __syncthreads();
    const int h = t & 127;
    const int gl0 = (t >> 7) * 8;
    float acc[8] = {0, 0, 0, 0, 0, 0, 0, 0};
    const float* w = W2 + h * 256;
    for (int o4 = 0; o4 < 64; ++o4) {
        float4 wvv = *(const float4*)(w + o4 * 4);
        #pragma unroll
        for (int gl = 0; gl < 8; ++gl) {
            const float* sr = &sx[(gl0 + gl) * 256 + o4 * 4];
            acc[gl] += sr[0] * wvv.x + sr[1] * wvv.y + sr[2] * wvv.z + sr[3] * wvv.w;
        }
    }
    float bb = b2[h];
    #pragma unroll
    for (int gl = 0; gl < 8; ++gl)
        y[(g0 + gl0 + gl) * 128 + h] = acc[gl] + bb;
}

extern "C" void kernel_launch(void* const* d_in, const int* in_sizes, int n_in,
                              void* d_out, int out_size, void* d_ws, size_t ws_size,
                              hipStream_t stream) {
    const float* x   = (const float*)d_in[0];
    const int* batch = (const int*)d_in[1];
    const float* W1  = (const float*)d_in[2];
    const float* b1  = (const float*)d_in[3];
    const float* W2  = (const float*)d_in[4];
    const float* b2  = (const float*)d_in[5];
    float* y = (float*)d_out;

    float* sumx = (float*)d_ws;                                                     // 4 MB @ 0
    unsigned short* W1b = (unsigned short*)((char*)d_ws + (size_t)NSEG * ODIM * 4); // 64 KB @ 4MB
    float* diag = (float*)((char*)d_ws + (8u << 20));                               // 2 MB @ 8MB

    zero_convert<<<dim3(NSEG), dim3(256), 0, stream>>>(W1, (unsigned int*)W1b, sumx);
    stage1<<<dim3(GRID1), dim3(256), 0, stream>>>(x, batch, W1b, b1, sumx);
    stage2<<<dim3(NSEG / 16), dim3(256), 0, stream>>>(sumx, W2, b2, y);
    // diagnostic (this round only): pure-read BW probe of x
    diag_read<<<dim3(2048), dim3(256), 0, stream>>>(x, diag);
}

// Round 15
// 279.067 us; speedup vs baseline: 1.1168x; 1.1168x over previous
//
#include <hip/hip_runtime.h>
#include <hip/hip_bf16.h>

#define NTOT 1048576
#define NSEG 4096
#define HDIM 128
#define ODIM 256
#define BN   64
#define GRID1 256
#define TPB  64          // tiles per block (64 x 64 rows = 4096 rows/block)
#define PSEG 40          // LDS partial-sum segment window (expected span ~17)

typedef __attribute__((ext_vector_type(8))) short bf16x8;
typedef __attribute__((ext_vector_type(4))) float f32x4;
typedef __attribute__((ext_vector_type(4))) unsigned int u32x4;

typedef const __attribute__((address_space(1))) unsigned int* gp_t;
typedef __attribute__((address_space(3))) unsigned int* lp_t;

// HW packed f32->bf16 RNE (no builtin on gfx950)
__device__ __forceinline__ unsigned int cvt_pk(float lo, float hi) {
    unsigned int r;
    asm("v_cvt_pk_bf16_f32 %0, %1, %2" : "=v"(r) : "v"(lo), "v"(hi));
    return r;
}

// zero sumx (1M floats) + convert W1 (32768 f32 -> 16384 packed u32), one dispatch
__global__ void zero_convert(const float* __restrict__ W1, unsigned int* __restrict__ W1b,
                             float* __restrict__ sumx) {
    int gid = blockIdx.x * 256 + threadIdx.x;
    sumx[gid] = 0.0f;
    if (gid < (ODIM * HDIM / 2)) {
        float2 v = *(const float2*)(W1 + 2 * gid);
        W1b[gid] = cvt_pk(v.x, v.y);
    }
}

// Ring-3 DMA pipeline with an EXACT vmcnt ladder: the main loop's only VMEM ops
// are DMA chunks (4/wave/tile). Segment sums go to an LDS partial window (no
// per-iter atomics -> no vmcnt pollution; R10/R8's hidden serializer). One
// atomic flush per block at the end. 512 thr = 8 waves x 32 output cols;
// LDS 152KB -> exactly 1 block/CU; in-flight 64KB/CU steady (Little's law).
__global__ __launch_bounds__(512, 1)
void stage1(const float* __restrict__ x, const int* __restrict__ batch,
            const unsigned short* __restrict__ W1b, const float* __restrict__ b1,
            float* __restrict__ sumx) {
    __shared__ __align__(16) float ring[3][BN * HDIM];   // 96 KB (3 x 32 KB tiles)
    __shared__ float part[PSEG * ODIM];                  // 40 KB partial sums
    __shared__ int segAll[TPB * BN];                     // 16 KB

    const int t    = threadIdx.x;
    const int lane = t & 63;
    const int wv   = t >> 6;            // 0..7
    const int l15  = lane & 15;
    const int lhi  = (lane >> 4) & 3;
    const int colbase = wv * 32;        // wave owns output cols [colbase, colbase+32)

    // dtype probe: int64 little-endian => odd (high) words are 0
    const bool is64 = (batch[NTOT - 1] == 0);
    const long r0 = (long)blockIdx.x * (TPB * BN);
    const char* xb = (const char*)(x + r0 * HDIM);
    const int segBase = batch[is64 ? 2 * r0 : r0];

    // ---- prologue part A: all non-DMA loads (drained before the ladder starts) ----
    for (int i = t; i < TPB * BN; i += 512) {
        long idx = r0 + i;
        segAll[i] = batch[is64 ? 2 * idx : idx];
    }
    for (int i = t; i < PSEG * ODIM; i += 512) part[i] = 0.f;

    bf16x8 bfr[2][4];   // [nf][ks]
    #pragma unroll
    for (int nf = 0; nf < 2; ++nf)
        #pragma unroll
        for (int ks = 0; ks < 4; ++ks)
            bfr[nf][ks] = *(const bf16x8*)(W1b + (colbase + nf * 16 + l15) * HDIM + ks * 32 + lhi * 8);
    float bias[2] = { b1[colbase + l15], b1[colbase + 16 + l15] };

    asm volatile("s_waitcnt vmcnt(0)" ::: "memory");   // ladder starts from 0 outstanding
    __builtin_amdgcn_sched_barrier(0);

    // DMA geometry: tile = 32 chunks x 1KB; wave wv owns chunks wv*4+j (j=0..3).
    // LDS dest linear (chunk*1024 + lane*16); global src granule-XOR pre-swizzled
    // so LDS[row][g] = x[row][g ^ (row&7)] (verified layout, R11).
    int soff[4], cbase[4];
    #pragma unroll
    for (int j = 0; j < 4; ++j) {
        int c   = wv * 4 + j;
        int row = 2 * c + (lane >> 5);
        int g   = lane & 31;
        soff[j]  = row * 512 + ((g << 4) ^ ((row & 7) << 4));
        cbase[j] = c * 1024;
    }

    // ---- prologue part B: issue tiles 0,1 into ring[0],ring[1] ----
    #pragma unroll
    for (int tt = 0; tt < 2; ++tt) {
        const char* src = xb + (size_t)tt * 32768;
        char* dst = (char*)&ring[tt][0];
        #pragma unroll
        for (int j = 0; j < 4; ++j)
            __builtin_amdgcn_global_load_lds((gp_t)(src + soff[j]), (lp_t)(dst + cbase[j]), 16, 0, 0);
    }
    __builtin_amdgcn_sched_barrier(0);
    asm volatile("s_waitcnt lgkmcnt(0)" ::: "memory");   // segAll/part visible
    __builtin_amdgcn_s_barrier();

    for (int g = 0; g < TPB; ++g) {
        const int bg = g % 3;

        // issue tile g+2 into ring[(g+2)%3] (freed by iter g-1's end barrier)
        if (g + 2 < TPB) {
            const char* src = xb + (size_t)(g + 2) * 32768;
            char* dst = (char*)&ring[(g + 2) % 3][0];
            #pragma unroll
            for (int j = 0; j < 4; ++j)
                __builtin_amdgcn_global_load_lds((gp_t)(src + soff[j]), (lp_t)(dst + cbase[j]), 16, 0, 0);
            __builtin_amdgcn_sched_barrier(0);
            // outstanding: unlanded of [g:4][g+1:4][g+2:4]; ladder EXACT (no atomics)
            asm volatile("s_waitcnt vmcnt(8)" ::: "memory");     // my tile-g chunks done
        } else if (g == TPB - 2) {
            asm volatile("s_waitcnt vmcnt(4)" ::: "memory");
        } else {
            asm volatile("s_waitcnt vmcnt(0)" ::: "memory");
        }
        __builtin_amdgcn_sched_barrier(0);
        __builtin_amdgcn_s_barrier();        // tile g complete in LDS for all waves
        __builtin_amdgcn_sched_barrier(0);

        // ---- compute tile g: MFMA (bias C-init) + tanh ----
        f32x4 acc[4][2];
        #pragma unroll
        for (int nf = 0; nf < 2; ++nf) {
            const float bb = bias[nf];
            #pragma unroll
            for (int mf = 0; mf < 4; ++mf)
                acc[mf][nf] = (f32x4){bb, bb, bb, bb};
        }
        const char* tile = (const char*)&ring[bg][0];
        #pragma unroll
        for (int ks = 0; ks < 4; ++ks) {
            #pragma unroll
            for (int mf = 0; mf < 4; ++mf) {
                const int m  = mf * 16 + l15;
                const int rb = m * 512;
                const int kb = ks * 128 + lhi * 32;
                const int sw = (m & 7) << 4;
                f32x4 u = *(const f32x4*)(tile + rb + (kb ^ sw));
                f32x4 v = *(const f32x4*)(tile + rb + ((kb + 16) ^ sw));
                u32x4 w;
                w.x = cvt_pk(u.x, u.y); w.y = cvt_pk(u.z, u.w);
                w.z = cvt_pk(v.x, v.y); w.w = cvt_pk(v.z, v.w);
                bf16x8 af = __builtin_bit_cast(bf16x8, w);
                #pragma unroll
                for (int nf = 0; nf < 2; ++nf)
                    acc[mf][nf] = __builtin_amdgcn_mfma_f32_16x16x32_bf16(af, bfr[nf][ks], acc[mf][nf], 0, 0, 0);
            }
        }
        #pragma unroll
        for (int mf = 0; mf < 4; ++mf)
            #pragma unroll
            for (int nf = 0; nf < 2; ++nf)
                #pragma unroll
                for (int r = 0; r < 4; ++r) {
                    float e = exp2f(acc[mf][nf][r] * 2.885390081777927f);
                    acc[mf][nf][r] = 1.0f - 2.0f * __builtin_amdgcn_rcpf(1.0f + e);
                }

        // ---- segmented reduction -> LDS partial window (no atomics in steady path) ----
        const int* segc = &segAll[g * BN];
        unsigned long long bmask;
        {
            int s_here = segc[lane];
            int s_prev = (lane > 0) ? segc[lane - 1] : s_here;
            bmask = __ballot(s_here != s_prev);
        }
        int start = 0;
        unsigned long long rem = bmask;
        for (;;) {
            const int end = rem ? (int)__builtin_ctzll(rem) : BN;
            const int sid = segc[start];
            float p0 = 0.f, p1 = 0.f;
            #pragma unroll
            for (int mf = 0; mf < 4; ++mf)
                #pragma unroll
                for (int r = 0; r < 4; ++r) {
                    int row = mf * 16 + lhi * 4 + r;
                    float w = ((unsigned)(row - start) < (unsigned)(end - start)) ? 1.0f : 0.0f;
                    p0 = fmaf(w, acc[mf][0][r], p0);
                    p1 = fmaf(w, acc[mf][1][r], p1);
                }
            p0 += __shfl_xor(p0, 16); p0 += __shfl_xor(p0, 32);
            p1 += __shfl_xor(p1, 16); p1 += __shfl_xor(p1, 32);
            if (lhi == 0) {
                const unsigned idx = (unsigned)(sid - segBase);
                if (idx < PSEG) {
                    // wave-private columns -> plain LDS RMW, conflict-free
                    float* p = &part[idx * ODIM + colbase + l15];
                    p[0]  += p0;
                    p[16] += p1;
                } else {
                    // overflow fallback (rare/never for this input); over-wait only
                    float* base = sumx + (long)sid * ODIM + colbase + l15;
                    atomicAdd(base, p0);
                    atomicAdd(base + 16, p1);
                }
            }
            if (rem == 0) break;
            start = end;
            rem &= rem - 1;
        }

        asm volatile("s_waitcnt lgkmcnt(0)" ::: "memory");  // my ds reads/writes retired
        __builtin_amdgcn_sched_barrier(0);
        __builtin_amdgcn_s_barrier();                       // ring[bg] free for reuse
        __builtin_amdgcn_sched_barrier(0);
    }

    // ---- flush partial window to sumx (one atomic pass per block) ----
    const int segLast = segAll[TPB * BN - 1];
    int nrows = segLast - segBase + 1;
    if (nrows > PSEG) nrows = PSEG;
    for (int i = t; i < nrows * ODIM; i += 512) {
        atomicAdd(&sumx[(long)(segBase + (i >> 8)) * ODIM + (i & 255)], part[i]);
    }
}

// y[g][h] = b2[h] + sum_o sumx[g][o] * W2[h][o]   (fp32, 268 MFLOP)
__global__ __launch_bounds__(256)
void stage2(const float* __restrict__ sumx, const float* __restrict__ W2,
            const float* __restrict__ b2, float* __restrict__ y) {
    __shared__ float sx[16 * 256];
    const int t = threadIdx.x;
    const long g0 = (long)blockIdx.x * 16;
    #pragma unroll
    for (int i = 0; i < 16; ++i)
        sx[i * 256 + t] = sumx[(g0 + i) * 256 + t];
    __syncthreads();
    const int h = t & 127;
    const int gl0 = (t >> 7) * 8;
    float acc[8] = {0, 0, 0, 0, 0, 0, 0, 0};
    const float* w = W2 + h * 256;
    for (int o4 = 0; o4 < 64; ++o4) {
        float4 wvv = *(const float4*)(w + o4 * 4);
        #pragma unroll
        for (int gl = 0; gl < 8; ++gl) {
            const float* sr = &sx[(gl0 + gl) * 256 + o4 * 4];
            acc[gl] += sr[0] * wvv.x + sr[1] * wvv.y + sr[2] * wvv.z + sr[3] * wvv.w;
        }
    }
    float bb = b2[h];
    #pragma unroll
    for (int gl = 0; gl < 8; ++gl)
        y[(g0 + gl0 + gl) * 128 + h] = acc[gl] + bb;
}

extern "C" void kernel_launch(void* const* d_in, const int* in_sizes, int n_in,
                              void* d_out, int out_size, void* d_ws, size_t ws_size,
                              hipStream_t stream) {
    const float* x   = (const float*)d_in[0];
    const int* batch = (const int*)d_in[1];
    const float* W1  = (const float*)d_in[2];
    const float* b1  = (const float*)d_in[3];
    const float* W2  = (const float*)d_in[4];
    const float* b2  = (const float*)d_in[5];
    float* y = (float*)d_out;

    float* sumx = (float*)d_ws;                                                     // 4 MB
    unsigned short* W1b = (unsigned short*)((char*)d_ws + (size_t)NSEG * ODIM * 4); // 64 KB

    zero_convert<<<dim3(NSEG), dim3(256), 0, stream>>>(W1, (unsigned int*)W1b, sumx);
    stage1<<<dim3(GRID1), dim3(512), 0, stream>>>(x, batch, W1b, b1, sumx);
    stage2<<<dim3(NSEG / 16), dim3(256), 0, stream>>>(sumx, W2, b2, y);
}

// Round 16
// 228.215 us; speedup vs baseline: 1.3656x; 1.2228x over previous
//
#include <hip/hip_runtime.h>
#include <hip/hip_bf16.h>

#define NTOT 1048576
#define NSEG 4096
#define HDIM 128
#define ODIM 256
#define BN   32          // rows per tile (16 KB)
#define TPB  16          // tiles per block -> 512 rows/block
#define GRID1 2048
#define PSEG 8           // LDS partial window (block spans ~3 segments)

typedef __attribute__((ext_vector_type(8))) short bf16x8;
typedef __attribute__((ext_vector_type(4))) float f32x4;
typedef __attribute__((ext_vector_type(4))) unsigned int u32x4;

typedef const __attribute__((address_space(1))) unsigned int* gp_t;
typedef __attribute__((address_space(3))) unsigned int* lp_t;

// HW packed f32->bf16 RNE (no builtin on gfx950)
__device__ __forceinline__ unsigned int cvt_pk(float lo, float hi) {
    unsigned int r;
    asm("v_cvt_pk_bf16_f32 %0, %1, %2" : "=v"(r) : "v"(lo), "v"(hi));
    return r;
}

// zero sumx (1M floats) + convert W1 (32768 f32 -> 16384 packed u32), one dispatch
__global__ void zero_convert(const float* __restrict__ W1, unsigned int* __restrict__ W1b,
                             float* __restrict__ sumx) {
    int gid = blockIdx.x * 256 + threadIdx.x;
    sumx[gid] = 0.0f;
    if (gid < (ODIM * HDIM / 2)) {
        float2 v = *(const float2*)(W1 + 2 * gid);
        W1b[gid] = cvt_pk(v.x, v.y);
    }
}

// R16: 32-row tiles, ring-3, issue 2 ahead (64 KB outstanding/CU), 2 blocks/CU.
// Exact vmcnt ladder (only DMAs counted; segment sums -> LDS partial window,
// one atomic flush per block at end). All layouts verified in R11.
__global__ __launch_bounds__(256, 2)
void stage1(const float* __restrict__ x, const int* __restrict__ batch,
            const unsigned short* __restrict__ W1b, const float* __restrict__ b1,
            float* __restrict__ sumx) {
    __shared__ __align__(16) float ring[3][BN * HDIM];   // 48 KB (3 x 16 KB)
    __shared__ float part[PSEG * ODIM];                  // 8 KB
    __shared__ int segAll[TPB * BN];                     // 2 KB (512 rows)

    const int t    = threadIdx.x;
    const int lane = t & 63;
    const int wv   = t >> 6;
    const int l15  = lane & 15;
    const int lhi  = (lane >> 4) & 3;

    // dtype probe: int64 little-endian => odd (high) words are 0
    const bool is64 = (batch[NTOT - 1] == 0);
    const long r0 = (long)blockIdx.x * (TPB * BN);
    const char* xb = (const char*)(x + r0 * HDIM);
    const int segBase = batch[is64 ? 2 * r0 : r0];

    // ---- prologue A: all non-DMA memory ops (drained before ladder starts) ----
    for (int i = t; i < TPB * BN; i += 256) {
        long idx = r0 + i;
        segAll[i] = batch[is64 ? 2 * idx : idx];
    }
    for (int i = t; i < PSEG * ODIM; i += 256) part[i] = 0.f;

    bf16x8 bfr[4][4];   // [nf][ks]; wave wv owns cols [wv*64, wv*64+64)
    #pragma unroll
    for (int nf = 0; nf < 4; ++nf)
        #pragma unroll
        for (int ks = 0; ks < 4; ++ks)
            bfr[nf][ks] = *(const bf16x8*)(W1b + (wv * 64 + nf * 16 + l15) * HDIM + ks * 32 + lhi * 8);
    float bias[4];
    #pragma unroll
    for (int nf = 0; nf < 4; ++nf) bias[nf] = b1[wv * 64 + nf * 16 + l15];

    asm volatile("s_waitcnt vmcnt(0) lgkmcnt(0)" ::: "memory");  // ladder baseline = 0
    __builtin_amdgcn_sched_barrier(0);

    // DMA geometry: tile = 16 chunks x 1KB; wave wv owns chunks wv*4+j.
    // chunk c covers rows 2c,2c+1 (lane>>5 picks the row, g=lane&31 the granule);
    // src granule XOR-swizzled within the row; LDS dest linear (verified, R11).
    int soff[4], cbase[4];
    #pragma unroll
    for (int j = 0; j < 4; ++j) {
        int c   = wv * 4 + j;
        int row = 2 * c + (lane >> 5);
        int g   = lane & 31;
        soff[j]  = row * 512 + ((g << 4) ^ ((row & 7) << 4));
        cbase[j] = c * 1024;
    }

    // ---- prologue B: issue tiles 0,1 ----
    #pragma unroll
    for (int tt = 0; tt < 2; ++tt) {
        const char* src = xb + (size_t)tt * (BN * HDIM * 4);
        char* dst = (char*)&ring[tt][0];
        #pragma unroll
        for (int j = 0; j < 4; ++j)
            __builtin_amdgcn_global_load_lds((gp_t)(src + soff[j]), (lp_t)(dst + cbase[j]), 16, 0, 0);
    }
    __builtin_amdgcn_sched_barrier(0);
    __builtin_amdgcn_s_barrier();        // segAll/part visible (lgkm drained above)

    for (int g = 0; g < TPB; ++g) {
        // issue tile g+2 into ring[(g+2)%3]; exact counted wait for tile g
        if (g + 2 < TPB) {
            const char* src = xb + (size_t)(g + 2) * (BN * HDIM * 4);
            char* dst = (char*)&ring[(g + 2) % 3][0];
            #pragma unroll
            for (int j = 0; j < 4; ++j)
                __builtin_amdgcn_global_load_lds((gp_t)(src + soff[j]), (lp_t)(dst + cbase[j]), 16, 0, 0);
            __builtin_amdgcn_sched_barrier(0);
            asm volatile("s_waitcnt vmcnt(8)" ::: "memory");   // {g+1,g+2} stay in flight
        } else if (g == TPB - 2) {
            asm volatile("s_waitcnt vmcnt(4)" ::: "memory");
        } else {
            asm volatile("s_waitcnt vmcnt(0)" ::: "memory");
        }
        __builtin_amdgcn_sched_barrier(0);
        __builtin_amdgcn_s_barrier();    // tile g complete in LDS for all waves
        __builtin_amdgcn_sched_barrier(0);

        // ---- compute tile g: 32 rows x 64 cols/wave ----
        f32x4 acc[2][4];
        #pragma unroll
        for (int nf = 0; nf < 4; ++nf) {
            const float bb = bias[nf];
            acc[0][nf] = (f32x4){bb, bb, bb, bb};
            acc[1][nf] = (f32x4){bb, bb, bb, bb};
        }
        const char* tile = (const char*)&ring[g % 3][0];
        #pragma unroll
        for (int ks = 0; ks < 4; ++ks) {
            #pragma unroll
            for (int mf = 0; mf < 2; ++mf) {
                const int m  = mf * 16 + l15;
                const int rb = m * 512;
                const int kb = ks * 128 + lhi * 32;
                const int sw = (m & 7) << 4;
                f32x4 u = *(const f32x4*)(tile + rb + (kb ^ sw));
                f32x4 v = *(const f32x4*)(tile + rb + ((kb + 16) ^ sw));
                u32x4 w;
                w.x = cvt_pk(u.x, u.y); w.y = cvt_pk(u.z, u.w);
                w.z = cvt_pk(v.x, v.y); w.w = cvt_pk(v.z, v.w);
                bf16x8 af = __builtin_bit_cast(bf16x8, w);
                #pragma unroll
                for (int nf = 0; nf < 4; ++nf)
                    acc[mf][nf] = __builtin_amdgcn_mfma_f32_16x16x32_bf16(af, bfr[nf][ks], acc[mf][nf], 0, 0, 0);
            }
        }
        // tanh(s) = 1 - 2/(1 + 2^(s*2*log2e))
        #pragma unroll
        for (int mf = 0; mf < 2; ++mf)
            #pragma unroll
            for (int nf = 0; nf < 4; ++nf)
                #pragma unroll
                for (int r = 0; r < 4; ++r) {
                    float e = exp2f(acc[mf][nf][r] * 2.885390081777927f);
                    acc[mf][nf][r] = 1.0f - 2.0f * __builtin_amdgcn_rcpf(1.0f + e);
                }

        // ---- segmented reduction -> LDS partial window (no atomics in ladder) ----
        const int* segc = &segAll[g * BN];
        const int ci = (lane < 31) ? lane : 31;          // clamp lanes >=32
        unsigned long long bmask;
        {
            int s_here = segc[ci];
            int s_prev = segc[ci - (ci > 0)];
            bmask = __ballot(s_here != s_prev) & 0xFFFFFFFFull;
        }
        int start = 0;
        unsigned long long rem = bmask;
        for (;;) {
            const int end = rem ? (int)__builtin_ctzll(rem) : BN;
            const int sid = segc[start];
            float p0 = 0.f, p1 = 0.f, p2 = 0.f, p3 = 0.f;
            #pragma unroll
            for (int mf = 0; mf < 2; ++mf)
                #pragma unroll
                for (int r = 0; r < 4; ++r) {
                    int row = mf * 16 + lhi * 4 + r;
                    float w = ((unsigned)(row - start) < (unsigned)(end - start)) ? 1.0f : 0.0f;
                    p0 = fmaf(w, acc[mf][0][r], p0);
                    p1 = fmaf(w, acc[mf][1][r], p1);
                    p2 = fmaf(w, acc[mf][2][r], p2);
                    p3 = fmaf(w, acc[mf][3][r], p3);
                }
            p0 += __shfl_xor(p0, 16); p0 += __shfl_xor(p0, 32);
            p1 += __shfl_xor(p1, 16); p1 += __shfl_xor(p1, 32);
            p2 += __shfl_xor(p2, 16); p2 += __shfl_xor(p2, 32);
            p3 += __shfl_xor(p3, 16); p3 += __shfl_xor(p3, 32);
            if (lhi == 0) {
                const unsigned idx = (unsigned)(sid - segBase);
                if (idx < PSEG) {
                    float* p = &part[idx * ODIM + wv * 64 + l15];
                    p[0]  += p0;
                    p[16] += p1;
                    p[32] += p2;
                    p[48] += p3;
                } else {   // effectively-never fallback; only causes over-wait
                    float* base = sumx + (long)sid * ODIM + wv * 64 + l15;
                    atomicAdd(base, p0);
                    atomicAdd(base + 16, p1);
                    atomicAdd(base + 32, p2);
                    atomicAdd(base + 48, p3);
                }
            }
            if (rem == 0) break;
            start = end;
            rem &= rem - 1;
        }

        asm volatile("s_waitcnt lgkmcnt(0)" ::: "memory");
        __builtin_amdgcn_sched_barrier(0);
        __builtin_amdgcn_s_barrier();    // ring[g%3] free for reuse
        __builtin_amdgcn_sched_barrier(0);
    }

    // ---- flush partial window (one atomic pass per block) ----
    const int segLast = segAll[TPB * BN - 1];
    int nrows = segLast - segBase + 1;
    if (nrows > PSEG) nrows = PSEG;
    for (int i = t; i < nrows * ODIM; i += 256)
        atomicAdd(&sumx[(long)(segBase + (i >> 8)) * ODIM + (i & 255)], part[i]);
}

// y[g][h] = b2[h] + sum_o sumx[g][o] * W2[h][o]   (fp32, 268 MFLOP)
__global__ __launch_bounds__(256)
void stage2(const float* __restrict__ sumx, const float* __restrict__ W2,
            const float* __restrict__ b2, float* __restrict__ y) {
    __shared__ float sx[16 * 256];
    const int t = threadIdx.x;
    const long g0 = (long)blockIdx.x * 16;
    #pragma unroll
    for (int i = 0; i < 16; ++i)
        sx[i * 256 + t] = sumx[(g0 + i) * 256 + t];
    __syncthreads();
    const int h = t & 127;
    const int gl0 = (t >> 7) * 8;
    float acc[8] = {0, 0, 0, 0, 0, 0, 0, 0};
    const float* w = W2 + h * 256;
    for (int o4 = 0; o4 < 64; ++o4) {
        float4 wvv = *(const float4*)(w + o4 * 4);
        #pragma unroll
        for (int gl = 0; gl < 8; ++gl) {
            const float* sr = &sx[(gl0 + gl) * 256 + o4 * 4];
            acc[gl] += sr[0] * wvv.x + sr[1] * wvv.y + sr[2] * wvv.z + sr[3] * wvv.w;
        }
    }
    float bb = b2[h];
    #pragma unroll
    for (int gl = 0; gl < 8; ++gl)
        y[(g0 + gl0 + gl) * 128 + h] = acc[gl] + bb;
}

extern "C" void kernel_launch(void* const* d_in, const int* in_sizes, int n_in,
                              void* d_out, int out_size, void* d_ws, size_t ws_size,
                              hipStream_t stream) {
    const float* x   = (const float*)d_in[0];
    const int* batch = (const int*)d_in[1];
    const float* W1  = (const float*)d_in[2];
    const float* b1  = (const float*)d_in[3];
    const float* W2  = (const float*)d_in[4];
    const float* b2  = (const float*)d_in[5];
    float* y = (float*)d_out;

    float* sumx = (float*)d_ws;                                                     // 4 MB
    unsigned short* W1b = (unsigned short*)((char*)d_ws + (size_t)NSEG * ODIM * 4); // 64 KB

    zero_convert<<<dim3(NSEG), dim3(256), 0, stream>>>(W1, (unsigned int*)W1b, sumx);
    stage1<<<dim3(GRID1), dim3(256), 0, stream>>>(x, batch, W1b, b1, sumx);
    stage2<<<dim3(NSEG / 16), dim3(256), 0, stream>>>(sumx, W2, b2, y);
}

// Round 17
// 202.849 us; speedup vs baseline: 1.5364x; 1.1250x over previous
//
#include <hip/hip_runtime.h>
#include <hip/hip_bf16.h>

#define NTOT 1048576
#define NSEG 4096
#define HDIM 128
#define ODIM 256
#define GRID1 2048        // blocks; 4 waves/block, 128 rows/wave, 512 rows/block
#define NSTEP 8           // 8 steps x 16 rows per wave

typedef __attribute__((ext_vector_type(8))) short bf16x8;
typedef __attribute__((ext_vector_type(4))) float f32x4;
typedef __attribute__((ext_vector_type(4))) unsigned int u32x4;

// HW packed f32->bf16 RNE (no builtin on gfx950)
__device__ __forceinline__ unsigned int cvt_pk(float lo, float hi) {
    unsigned int r;
    asm("v_cvt_pk_bf16_f32 %0, %1, %2" : "=v"(r) : "v"(lo), "v"(hi));
    return r;
}

// zero sumx (1M floats) + convert W1 (32768 f32 -> 16384 packed u32), one dispatch
__global__ void zero_convert(const float* __restrict__ W1, unsigned int* __restrict__ W1b,
                             float* __restrict__ sumx) {
    int gid = blockIdx.x * 256 + threadIdx.x;
    sumx[gid] = 0.0f;
    if (gid < (ODIM * HDIM / 2)) {
        float2 v = *(const float2*)(W1 + 2 * gid);
        W1b[gid] = cvt_pk(v.x, v.y);
    }
}

// R17: free-running row-slice kernel. W1 (64KB bf16) lives in LDS (read-only,
// XOR-swizzled, staged once -> ONE barrier total). Each wave owns 128 distinct
// rows (8 steps x 16), loads x straight to registers (prefetch 1 step ahead,
// ping-pong), computes all 256 output cols via MFMA with B from LDS, and does
// the sorted-segment reduce with a cross-step register carry (one atomic burst
// per segment per wave). Zero main-loop barriers => waves free-run like the
// R14 diag_read that measured 5.07 TB/s.
__global__ __launch_bounds__(256, 2)
void stage1(const float* __restrict__ x, const int* __restrict__ batch,
            const unsigned short* __restrict__ W1b, const float* __restrict__ b1,
            float* __restrict__ sumx) {
    __shared__ __align__(16) unsigned char w1s[ODIM * HDIM * 2];   // 64 KB

    const int t    = threadIdx.x;
    const int lane = t & 63;
    const int wv   = t >> 6;
    const int l15  = lane & 15;
    const int lhi  = (lane >> 4) & 3;

    // dtype probe: int64 little-endian => odd (high) words are 0
    const bool is64 = (batch[NTOT - 1] == 0);

    // ---- stage W1 -> LDS, XOR-swizzled (verified swizzle: byte ^= (row&7)<<4) ----
    for (int c = t; c < 4096; c += 256) {           // 4096 x 16B chunks
        u32x4 v = ((const u32x4*)W1b)[c];
        int row = c >> 4;                           // 16 chunks per 256B row
        int kb  = (c & 15) * 16;
        *(u32x4*)(w1s + row * 256 + (kb ^ ((row & 7) << 4))) = v;
    }
    float bias[16];
    #pragma unroll
    for (int nf = 0; nf < 16; ++nf) bias[nf] = b1[nf * 16 + l15];
    __syncthreads();                                // the only block barrier

    // per-ks LDS read base (imm offset nf*4096 walks the 16 col-fragments)
    int lra[4];
    #pragma unroll
    for (int ks = 0; ks < 4; ++ks)
        lra[ks] = l15 * 256 + ((ks * 64 + lhi * 16) ^ ((l15 & 7) << 4));

    const long rowbase = (long)blockIdx.x * 512 + (long)wv * 128;
    const char* xrow = (const char*)x + (rowbase + l15) * 512 + lhi * 32;

    int curSeg = batch[is64 ? 2 * rowbase : rowbase];
    float runsum[16];
    #pragma unroll
    for (int nf = 0; nf < 16; ++nf) runsum[nf] = 0.f;

#define FLUSH()                                                                  \
    do { if (lhi == 0) {                                                         \
            float* _b = sumx + (long)curSeg * ODIM + l15;                        \
            _Pragma("unroll")                                                    \
            for (int nf = 0; nf < 16; ++nf) atomicAdd(_b + nf * 16, runsum[nf]); \
        }                                                                        \
        _Pragma("unroll")                                                        \
        for (int nf = 0; nf < 16; ++nf) runsum[nf] = 0.f;                        \
    } while (0)

#define LOADSTEP(dst, s)                                                          \
    do { const char* _p = xrow + (size_t)(s) * 8192;                              \
        _Pragma("unroll")                                                         \
        for (int ks = 0; ks < 4; ++ks) {                                          \
            dst[2*ks]   = *(const f32x4*)(_p + ks * 128);                         \
            dst[2*ks+1] = *(const f32x4*)(_p + ks * 128 + 16);                    \
        }                                                                         \
    } while (0)

#define STEP(s, cur, nxt)                                                         \
    do {                                                                          \
        if ((s) + 1 < NSTEP) LOADSTEP(nxt, (s) + 1);   /* prefetch, lands during compute */ \
        const long _r0 = rowbase + (long)(s) * 16;                                \
        int seg_l = batch[is64 ? 2 * (_r0 + l15) : (_r0 + l15)];                  \
        int prv   = __shfl(seg_l, lane > 0 ? lane - 1 : 0);                       \
        unsigned bm = (unsigned)(__ballot(seg_l != prv)) & 0xFFFEu;               \
        int seg0 = __shfl(seg_l, 0);                                              \
        f32x4 acc[16];                                                            \
        _Pragma("unroll")                                                         \
        for (int nf = 0; nf < 16; ++nf)                                           \
            acc[nf] = (f32x4){bias[nf], bias[nf], bias[nf], bias[nf]};            \
        _Pragma("unroll")                                                         \
        for (int ks = 0; ks < 4; ++ks) {                                          \
            u32x4 w;                                                              \
            w.x = cvt_pk(cur[2*ks].x,   cur[2*ks].y);                             \
            w.y = cvt_pk(cur[2*ks].z,   cur[2*ks].w);                             \
            w.z = cvt_pk(cur[2*ks+1].x, cur[2*ks+1].y);                           \
            w.w = cvt_pk(cur[2*ks+1].z, cur[2*ks+1].w);                           \
            bf16x8 af = __builtin_bit_cast(bf16x8, w);                            \
            _Pragma("unroll")                                                     \
            for (int nf = 0; nf < 16; ++nf) {                                     \
                bf16x8 bf = *(const bf16x8*)(w1s + lra[ks] + nf * 4096);          \
                acc[nf] = __builtin_amdgcn_mfma_f32_16x16x32_bf16(af, bf, acc[nf], 0, 0, 0); \
            }                                                                     \
        }                                                                         \
        _Pragma("unroll")                                                         \
        for (int nf = 0; nf < 16; ++nf)                                           \
            _Pragma("unroll")                                                     \
            for (int r = 0; r < 4; ++r) {                                         \
                float e = exp2f(acc[nf][r] * 2.885390081777927f);                 \
                acc[nf][r] = 1.0f - 2.0f * __builtin_amdgcn_rcpf(1.0f + e);       \
            }                                                                     \
        if (seg0 != curSeg) { FLUSH(); curSeg = seg0; }                           \
        int start = 0;                                                            \
        unsigned rem = bm;                                                        \
        for (;;) {                                                                \
            const int end = rem ? (int)__builtin_ctz(rem) : 16;                   \
            _Pragma("unroll")                                                     \
            for (int nf = 0; nf < 16; ++nf) {                                     \
                float sp = 0.f;                                                   \
                _Pragma("unroll")                                                 \
                for (int r = 0; r < 4; ++r) {                                     \
                    int row = lhi * 4 + r;                                        \
                    float wgt = ((unsigned)(row - start) < (unsigned)(end - start)) ? 1.0f : 0.0f; \
                    sp = fmaf(wgt, acc[nf][r], sp);                               \
                }                                                                 \
                sp += __shfl_xor(sp, 16);                                         \
                sp += __shfl_xor(sp, 32);                                         \
                runsum[nf] += sp;                                                 \
            }                                                                     \
            if (end == 16) break;                                                 \
            FLUSH();                                                              \
            curSeg = __shfl(seg_l, end);                                          \
            rem &= rem - 1;                                                       \
            start = end;                                                          \
        }                                                                         \
    } while (0)

    f32x4 cA[8], cB[8];
    LOADSTEP(cA, 0);
    #pragma unroll
    for (int s = 0; s < NSTEP; s += 2) {
        STEP(s, cA, cB);
        STEP(s + 1, cB, cA);
    }
    FLUSH();   // final segment carry

#undef STEP
#undef LOADSTEP
#undef FLUSH
}

// y[g][h] = b2[h] + sum_o sumx[g][o] * W2[h][o]   (fp32, 268 MFLOP)
__global__ __launch_bounds__(256)
void stage2(const float* __restrict__ sumx, const float* __restrict__ W2,
            const float* __restrict__ b2, float* __restrict__ y) {
    __shared__ float sx[16 * 256];
    const int t = threadIdx.x;
    const long g0 = (long)blockIdx.x * 16;
    #pragma unroll
    for (int i = 0; i < 16; ++i)
        sx[i * 256 + t] = sumx[(g0 + i) * 256 + t];
    __syncthreads();
    const int h = t & 127;
    const int gl0 = (t >> 7) * 8;
    float acc[8] = {0, 0, 0, 0, 0, 0, 0, 0};
    const float* w = W2 + h * 256;
    for (int o4 = 0; o4 < 64; ++o4) {
        float4 wvv = *(const float4*)(w + o4 * 4);
        #pragma unroll
        for (int gl = 0; gl < 8; ++gl) {
            const float* sr = &sx[(gl0 + gl) * 256 + o4 * 4];
            acc[gl] += sr[0] * wvv.x + sr[1] * wvv.y + sr[2] * wvv.z + sr[3] * wvv.w;
        }
    }
    float bb = b2[h];
    #pragma unroll
    for (int gl = 0; gl < 8; ++gl)
        y[(g0 + gl0 + gl) * 128 + h] = acc[gl] + bb;
}

extern "C" void kernel_launch(void* const* d_in, const int* in_sizes, int n_in,
                              void* d_out, int out_size, void* d_ws, size_t ws_size,
                              hipStream_t stream) {
    const float* x   = (const float*)d_in[0];
    const int* batch = (const int*)d_in[1];
    const float* W1  = (const float*)d_in[2];
    const float* b1  = (const float*)d_in[3];
    const float* W2  = (const float*)d_in[4];
    const float* b2  = (const float*)d_in[5];
    float* y = (float*)d_out;

    float* sumx = (float*)d_ws;                                                     // 4 MB
    unsigned short* W1b = (unsigned short*)((char*)d_ws + (size_t)NSEG * ODIM * 4); // 64 KB

    zero_convert<<<dim3(NSEG), dim3(256), 0, stream>>>(W1, (unsigned int*)W1b, sumx);
    stage1<<<dim3(GRID1), dim3(256), 0, stream>>>(x, batch, W1b, b1, sumx);
    stage2<<<dim3(NSEG / 16), dim3(256), 0, stream>>>(sumx, W2, b2, y);
}